// Round 4
// baseline (107.062 us; speedup 1.0000x reference)
//
#include <hip/hip_runtime.h>
#include <hip/hip_bf16.h>
#include <math.h>

#define KMIX 16
#define DIM  16
#define TPW  8          // 16-sample tiles per wave in gmm_main
#define TRI_IDX(i,j) (((i)*((i)+1))/2 + (j))

typedef _Float16 half8 __attribute__((ext_vector_type(8)));
typedef float    f32x4 __attribute__((ext_vector_type(4)));

// ---------------------------------------------------------------------------
// Precompute: ONE wave. Lane k<16 factors Sigma_k = L L^T and inverts L
// IN PLACE in a single packed triangular array a[136] (~170 live floats vs
// R3's 320+ -> no scratch spill; spills on the 1-wave serial chain were the
// ~40 us pathology). Ordering proof for in-place trinv: process c ascending,
// r ascending; entry (r,c) reads L[r][m] m in [c,r-1] (cols > c untouched;
// m=c read before overwrite) and li[m][c] (already written above).
// Outputs (unchanged vs R3):
//   wsA[mix][lane] = half8 A-operand frag of W~ = [L^{-1} | -b | 0]
//   wsC[mix]       = Phi / sqrt(2*pi*det)
// ---------------------------------------------------------------------------
__global__ __launch_bounds__(64) void gmm_precompute(
    const float* __restrict__ Phi, const float* __restrict__ mu,
    const float* __restrict__ Sigma,
    _Float16* __restrict__ wsA, float* __restrict__ wsC)
{
    __shared__ float sLi[KMIX][DIM][DIM];   // L^{-1}, upper part zeroed
    __shared__ float sNB[KMIX][DIM];        // -b
    const int lane = threadIdx.x;

    if (lane < KMIX) {
        const int k = lane;
        float a[136], rd[DIM];

        #pragma unroll
        for (int i = 0; i < DIM; ++i)
            #pragma unroll
            for (int j = 0; j <= i; ++j)
                a[TRI_IDX(i, j)] = Sigma[k * 256 + i * 16 + j];

        // Left-looking Cholesky, in place, reciprocal diagonal kept.
        #pragma unroll
        for (int i = 0; i < DIM; ++i) {
            #pragma unroll
            for (int j = 0; j <= i; ++j) {
                float s = a[TRI_IDX(i, j)];
                #pragma unroll
                for (int m = 0; m < j; ++m)
                    s -= a[TRI_IDX(i, m)] * a[TRI_IDX(j, m)];
                if (j == i) {
                    const float d = __builtin_amdgcn_sqrtf(s);
                    a[TRI_IDX(i, i)] = d;
                    rd[i] = __builtin_amdgcn_rcpf(d);
                } else {
                    a[TRI_IDX(i, j)] = s * rd[j];
                }
            }
        }

        // In-place triangular inversion: a <- L^{-1}.
        #pragma unroll
        for (int c = 0; c < DIM; ++c) {
            a[TRI_IDX(c, c)] = rd[c];
            #pragma unroll
            for (int r = c + 1; r < DIM; ++r) {
                float s = 0.0f;
                #pragma unroll
                for (int m = c; m < r; ++m)
                    s += a[TRI_IDX(r, m)] * a[TRI_IDX(m, c)];
                a[TRI_IDX(r, c)] = -s * rd[r];
            }
        }

        // coeff = Phi / (sqrt(2*pi) * prod(diag L))
        float invd = 1.0f;
        #pragma unroll
        for (int i = 0; i < DIM; ++i) invd *= rd[i];
        wsC[k] = Phi[k] * 0.3989422804014327f * invd;

        // b = L^{-1} mu; publish L^{-1} (zero-padded) and -b to LDS
        float mv[DIM];
        #pragma unroll
        for (int j = 0; j < DIM; ++j) mv[j] = mu[k * DIM + j];
        #pragma unroll
        for (int r = 0; r < DIM; ++r) {
            float b = 0.0f;
            #pragma unroll
            for (int j = 0; j <= r; ++j) b += a[TRI_IDX(r, j)] * mv[j];
            sNB[k][r] = -b;
            #pragma unroll
            for (int j = 0; j < DIM; ++j)
                sLi[k][r][j] = (j <= r) ? a[TRI_IDX(r, j)] : 0.0f;
        }
    }
    __syncthreads();

    // All 64 lanes: pack A-operand fragments (verified 16x16x32 A layout:
    // A[m = lane&15][k = quad*8 + j]).
    const int m = lane & 15;
    const int quad = lane >> 4;
    for (int mix = 0; mix < KMIX; ++mix) {
        half8 h;
        #pragma unroll
        for (int j = 0; j < 8; ++j) {
            float v;
            if (quad == 0)      v = sLi[mix][m][j];
            else if (quad == 1) v = sLi[mix][m][8 + j];
            else if (quad == 2) v = (j == 0) ? sNB[mix][m] : 0.0f;
            else                v = 0.0f;
            h[j] = (_Float16)v;
        }
        ((half8*)wsA)[mix * 64 + lane] = h;
    }
}

// ---------------------------------------------------------------------------
// Main (unchanged from R3, verified): per wave, per 16-sample tile: build
// B frag = [x;1;0-pad] columns, one MFMA per mixture -> y[comp][sample],
// q = sum comp y^2 via 4 square-FMAs + shfl_xor(16) + shfl_xor(32),
// then sum_k c_k exp(-q/2).
// ---------------------------------------------------------------------------
__global__ __launch_bounds__(256) void gmm_main(
    const float* __restrict__ samples,
    const _Float16* __restrict__ wsA, const float* __restrict__ wsC,
    float* __restrict__ out, int N, int ntiles)
{
    const int lane = threadIdx.x & 63;
    const int wave = blockIdx.x * (blockDim.x >> 6) + (threadIdx.x >> 6);
    const int n = lane & 15;          // sample column within tile
    const int quad = lane >> 4;

    // Loop-invariant: A fragments (16 mixtures) + coefficients.
    half8 afrag[KMIX];
    #pragma unroll
    for (int mix = 0; mix < KMIX; ++mix)
        afrag[mix] = ((const half8*)wsA)[mix * 64 + lane];
    float ck[KMIX];
    #pragma unroll
    for (int mix = 0; mix < KMIX; ++mix) ck[mix] = wsC[mix];

    const f32x4 zero = {0.0f, 0.0f, 0.0f, 0.0f};

    for (int t = 0; t < TPW; ++t) {
        const int tile = wave * TPW + t;
        if (tile >= ntiles) break;
        const int s0 = tile * 16;

        // B frag: B[k = quad*8+j][n] = x~[sample n][k]
        half8 bfrag;
        #pragma unroll
        for (int j = 0; j < 8; ++j) bfrag[j] = (_Float16)0.0f;
        if (quad < 2) {
            int sidx = s0 + n; if (sidx >= N) sidx = N - 1;
            const float4* p = (const float4*)(samples + (size_t)sidx * DIM + quad * 8);
            const float4 u = p[0], v = p[1];
            bfrag[0] = (_Float16)u.x; bfrag[1] = (_Float16)u.y;
            bfrag[2] = (_Float16)u.z; bfrag[3] = (_Float16)u.w;
            bfrag[4] = (_Float16)v.x; bfrag[5] = (_Float16)v.y;
            bfrag[6] = (_Float16)v.z; bfrag[7] = (_Float16)v.w;
        } else if (quad == 2) {
            bfrag[0] = (_Float16)1.0f;   // augmented k=16 -> folds -b
        }

        float sum = 0.0f;
        #pragma unroll
        for (int mix = 0; mix < KMIX; ++mix) {
            const f32x4 d = __builtin_amdgcn_mfma_f32_16x16x32_f16(
                afrag[mix], bfrag, zero, 0, 0, 0);
            float q = d[0] * d[0];
            q = fmaf(d[1], d[1], q);
            q = fmaf(d[2], d[2], q);
            q = fmaf(d[3], d[3], q);
            q += __shfl_xor(q, 16, 64);
            q += __shfl_xor(q, 32, 64);
            sum = fmaf(ck[mix], __expf(-0.5f * q), sum);
        }

        const int sidx = s0 + n;
        if (quad == 0 && sidx < N) out[sidx] = -__logf(sum);
    }
}

extern "C" void kernel_launch(void* const* d_in, const int* in_sizes, int n_in,
                              void* d_out, int out_size, void* d_ws, size_t ws_size,
                              hipStream_t stream)
{
    const float* samples = (const float*)d_in[0];
    const float* Phi     = (const float*)d_in[1];
    const float* mu      = (const float*)d_in[2];
    const float* Sigma   = (const float*)d_in[3];
    float* out = (float*)d_out;
    const int N = in_sizes[0] / DIM;

    _Float16* wsA = (_Float16*)d_ws;                       // 16*64*8 halves = 16 KB
    float* wsC = (float*)((char*)d_ws + KMIX * 64 * 8 * sizeof(_Float16));

    gmm_precompute<<<1, 64, 0, stream>>>(Phi, mu, Sigma, wsA, wsC);

    const int ntiles = (N + 15) / 16;
    const int waves  = (ntiles + TPW - 1) / TPW;
    const int blocks = (waves + 3) / 4;
    gmm_main<<<blocks, 256, 0, stream>>>(samples, wsA, wsC, out, N, ntiles);
}